// Round 5
// baseline (765.885 us; speedup 1.0000x reference)
//
#include <hip/hip_runtime.h>
#include <cstdint>
#include <cstddef>

// PaperRNNHead on MI355X — round 5: 4-wave (n=32,m=64) 32x32x16-MFMA split-bf16.
// Rationale: LDS pipe is the critical path. 8-wave n16 design read h planes
// with 8x redundancy (1280 ds_read_b128/step/block). 4 waves x n32 halves that
// (640), weights = 320 VGPR/wave (only fits at 4 waves: 2048-reg CU file).
// fc is computed from layer-2 accumulators in-register (shfl_xor + small LDS
// reduce) instead of re-reading h2. Biases/pos-weights/fcW live in LDS consts.

#define BATCH    65536
#define CTXF     512
#define INF      514
#define HID      128
#define PREDL    12
#define OBSL     8
#define BM       64
#define NTHREADS 256
#define NWAVES   4

typedef __attribute__((ext_vector_type(8)))  short s16x8;
typedef __attribute__((ext_vector_type(4)))  float f32x4;
typedef __attribute__((ext_vector_type(16))) float f32x16;

#define MFMA32(a, b, c) __builtin_amdgcn_mfma_f32_32x32x16_bf16((a), (b), (c), 0, 0, 0)

__device__ __forceinline__ unsigned int cvt_pk(float a, float b) {
    unsigned int r;
    asm("v_cvt_pk_bf16_f32 %0, %1, %2" : "=v"(r) : "v"(a), "v"(b));
    return r;  // [15:0] = bf16(a), [31:16] = bf16(b)
}
__device__ __forceinline__ float ubf(unsigned int bits) { return __uint_as_float(bits); }

union Frag { unsigned int u[4]; s16x8 v; };

// split 8 consecutive fp32 into hi/lo bf16x8 fragments
__device__ __forceinline__ void split8(const float* x, s16x8& hi, s16x8& lo) {
    Frag H, L;
#pragma unroll
    for (int i = 0; i < 4; ++i) {
        unsigned int hp = cvt_pk(x[2 * i], x[2 * i + 1]);
        float r0 = x[2 * i]     - ubf(hp << 16);
        float r1 = x[2 * i + 1] - ubf(hp & 0xffff0000u);
        H.u[i] = hp;
        L.u[i] = cvt_pk(r0, r1);
    }
    hi = H.v; lo = L.v;
}

// tanh(x) = 1 - 2/(exp(2x)+1)
__device__ __forceinline__ float fast_tanh(float x) {
    float e = __expf(x + x);
    float r = __builtin_amdgcn_rcpf(e + 1.0f);
    return fmaf(-2.0f, r, 1.0f);
}

// Load a 128x128 weight matrix's A-fragments for this wave (rows n0..n0+31),
// 32x32x16 layout: lane holds row n0+(lane&31), k = kt*16 + (lane>>5)*8 .. +7.
__device__ __forceinline__ void load_w32(const float* __restrict__ W,
                                         int n0, int lane, s16x8* hi, s16x8* lo) {
    const float* base = W + (size_t)(n0 + (lane & 31)) * HID + ((lane >> 5) * 8);
#pragma unroll
    for (int kt = 0; kt < 8; ++kt) {
        float x[8];
        *(float4*)(x)     = *(const float4*)(base + kt * 16);
        *(float4*)(x + 4) = *(const float4*)(base + kt * 16 + 4);
        split8(x, hi[kt], lo[kt]);
    }
}

// acc0/acc1 (m-tiles 0/1) += W x h, 3-term split-bf16.
// h planes [64][128] shorts, swizzled short_idx ^= (m&7)<<3.
__device__ __forceinline__ void mat_pass32(f32x16& acc0, f32x16& acc1,
                                           const s16x8* whi, const s16x8* wlo,
                                           const unsigned short* __restrict__ phi,
                                           const unsigned short* __restrict__ plo,
                                           int lane) {
    const int m31 = lane & 31;
    const int hb  = lane >> 5;
    const int sx  = (m31 & 7) << 3;
#pragma unroll
    for (int kt = 0; kt < 8; ++kt) {
        const int ks = (kt * 16 + hb * 8) ^ sx;
        {
            const int idx = m31 * HID + ks;
            s16x8 bh = *reinterpret_cast<const s16x8*>(&phi[idx]);
            s16x8 bl = *reinterpret_cast<const s16x8*>(&plo[idx]);
            acc0 = MFMA32(whi[kt], bh, acc0);
            acc0 = MFMA32(whi[kt], bl, acc0);
            acc0 = MFMA32(wlo[kt], bh, acc0);
        }
        {
            const int idx = (m31 + 32) * HID + ks;
            s16x8 bh = *reinterpret_cast<const s16x8*>(&phi[idx]);
            s16x8 bl = *reinterpret_cast<const s16x8*>(&plo[idx]);
            acc1 = MFMA32(whi[kt], bh, acc1);
            acc1 = MFMA32(whi[kt], bl, acc1);
            acc1 = MFMA32(wlo[kt], bh, acc1);
        }
    }
}

// cst rows: 0 wp0, 1 wp1, 2 b1, 3 b2, 4 fcw0, 5 fcw1, 6 b0
__global__ void __launch_bounds__(NTHREADS, 1)
rnn_head_kernel(const float* __restrict__ raw_ctx,
                const float* __restrict__ obs_traj,
                const float* __restrict__ Wih0, const float* __restrict__ Whh0,
                const float* __restrict__ bih0, const float* __restrict__ bhh0,
                const float* __restrict__ Wih1, const float* __restrict__ Whh1,
                const float* __restrict__ bih1, const float* __restrict__ bhh1,
                const float* __restrict__ Wih2, const float* __restrict__ Whh2,
                const float* __restrict__ bih2, const float* __restrict__ bhh2,
                const float* __restrict__ fcW,  const float* __restrict__ fcb,
                float* __restrict__ out)
{
    __shared__ __align__(16) unsigned short h_hi[3][BM * HID];   // 48 KB
    __shared__ __align__(16) unsigned short h_lo[3][BM * HID];   // 48 KB
    __shared__ __align__(16) float ctx_s[BM][132];               // 33.8 KB
    __shared__ __align__(16) float cst[7][HID];                  // 3.5 KB
    __shared__ float2 pbuf[BM];
    __shared__ float2 pfc[NWAVES][BM];

    const int tid  = threadIdx.x;
    const int lane = tid & 63;
    const int wid  = __builtin_amdgcn_readfirstlane(tid >> 6);   // 0..3
    const int n0   = wid * 32;
    const int row0 = blockIdx.x * BM;
    const int m31  = lane & 31;
    const int hb   = lane >> 5;
    const int sx   = (m31 & 7) << 3;

    // ---------- init LDS ----------
    if (tid < HID) {
        cst[0][tid] = Wih0[(size_t)tid * INF + 512];
        cst[1][tid] = Wih0[(size_t)tid * INF + 513];
        cst[2][tid] = bih1[tid] + bhh1[tid];
        cst[3][tid] = bih2[tid] + bhh2[tid];
        cst[4][tid] = fcW[tid];
        cst[5][tid] = fcW[HID + tid];
        cst[6][tid] = bih0[tid] + bhh0[tid];
    }
    if (tid < BM) {
        pbuf[tid] = *reinterpret_cast<const float2*>(
            &obs_traj[((size_t)(OBSL - 1) * BATCH + row0 + tid) * 2]);
    }
    for (int i = tid; i < 3 * BM * HID / 2; i += NTHREADS) {
        ((unsigned int*)h_hi)[i] = 0u;
        ((unsigned int*)h_lo)[i] = 0u;
    }
    const float fcb0 = fcb[0], fcb1 = fcb[1];
    __syncthreads();

    // ---------- ctxc = b0 + raw_ctx @ Wih0[:, :512].T  (D-layout registers) ----------
    f32x16 ctxc0, ctxc1;
#pragma unroll
    for (int rg = 0; rg < 4; ++rg) {
        f32x4 v = *reinterpret_cast<const f32x4*>(&cst[6][n0 + rg * 8 + hb * 4]);
#pragma unroll
        for (int r = 0; r < 4; ++r) ctxc0[rg * 4 + r] = v[r];
    }
    ctxc1 = ctxc0;

#pragma unroll 1
    for (int kc = 0; kc < CTXF; kc += 128) {
        // A-side: Wih0 chunk fragments (global, one-time)
        s16x8 cah[8], cal[8];
        {
            const float* base = Wih0 + (size_t)(n0 + m31) * INF + kc + hb * 8;
#pragma unroll
            for (int kt = 0; kt < 8; ++kt) {
                float x[8];
                *(float4*)(x)     = *(const float4*)(base + kt * 16);
                *(float4*)(x + 4) = *(const float4*)(base + kt * 16 + 4);
                split8(x, cah[kt], cal[kt]);
            }
        }
        __syncthreads();   // previous chunk's ctx_s reads done
        {   // stage 64x128 fp32 chunk (coalesced: 4 threads span one 512B row)
            const int rr  = tid >> 2;
            const int seg = (tid & 3) * 32;
            const float* src = raw_ctx + (size_t)(row0 + rr) * CTXF + kc + seg;
            float* dst = &ctx_s[rr][seg];
#pragma unroll
            for (int j = 0; j < 8; ++j)
                ((float4*)dst)[j] = ((const float4*)src)[j];
        }
        __syncthreads();
#pragma unroll
        for (int kt = 0; kt < 8; ++kt) {
            const int k0 = kt * 16 + hb * 8;
            {
                float x[8];
                *(float4*)(x)     = *(const float4*)&ctx_s[m31][k0];
                *(float4*)(x + 4) = *(const float4*)&ctx_s[m31][k0 + 4];
                s16x8 bh, bl; split8(x, bh, bl);
                ctxc0 = MFMA32(cah[kt], bh, ctxc0);
                ctxc0 = MFMA32(cah[kt], bl, ctxc0);
                ctxc0 = MFMA32(cal[kt], bh, ctxc0);
            }
            {
                float x[8];
                *(float4*)(x)     = *(const float4*)&ctx_s[m31 + 32][k0];
                *(float4*)(x + 4) = *(const float4*)&ctx_s[m31 + 32][k0 + 4];
                s16x8 bh, bl; split8(x, bh, bl);
                ctxc1 = MFMA32(cah[kt], bh, ctxc1);
                ctxc1 = MFMA32(cah[kt], bl, ctxc1);
                ctxc1 = MFMA32(cal[kt], bh, ctxc1);
            }
        }
    }

    // ---------- persistent weight fragments (320 VGPR) ----------
    s16x8 whh0h[8], whh0l[8], wih1h[8], wih1l[8], whh1h[8], whh1l[8];
    s16x8 wih2h[8], wih2l[8], whh2h[8], whh2l[8];
    load_w32(Whh0, n0, lane, whh0h, whh0l);
    load_w32(Wih1, n0, lane, wih1h, wih1l);
    load_w32(Whh1, n0, lane, whh1h, whh1l);
    load_w32(Wih2, n0, lane, wih2h, wih2l);
    load_w32(Whh2, n0, lane, whh2h, whh2l);
    __syncthreads();

    // ---------- 12 recurrent steps ----------
#pragma unroll 1
    for (int s = 0; s < PREDL; ++s) {
        f32x16 a0 = ctxc0, a1 = ctxc1;

        // ===== layer 0: tanh(ctxc + pos + Whh0 @ h0_old) =====
        mat_pass32(a0, a1, whh0h, whh0l, h_hi[0], h_lo[0], lane);
        __syncthreads();                       // h0_old reads done
#pragma unroll
        for (int mt = 0; mt < 2; ++mt) {
            const int m = mt * 32 + m31;
            const float2 p = pbuf[m];
            const f32x16& A = mt ? a1 : a0;
#pragma unroll
            for (int rg = 0; rg < 4; ++rg) {
                const int nb4 = n0 + rg * 8 + hb * 4;
                f32x4 w0 = *reinterpret_cast<const f32x4*>(&cst[0][nb4]);
                f32x4 w1 = *reinterpret_cast<const f32x4*>(&cst[1][nb4]);
                float t[4];
#pragma unroll
                for (int r = 0; r < 4; ++r)
                    t[r] = fast_tanh(A[rg * 4 + r] + p.x * w0[r] + p.y * w1[r]);
                unsigned int hp0 = cvt_pk(t[0], t[1]), hp1 = cvt_pk(t[2], t[3]);
                unsigned int lp0 = cvt_pk(t[0] - ubf(hp0 << 16), t[1] - ubf(hp0 & 0xffff0000u));
                unsigned int lp1 = cvt_pk(t[2] - ubf(hp1 << 16), t[3] - ubf(hp1 & 0xffff0000u));
                const int idx = m * HID + (nb4 ^ sx);
                *reinterpret_cast<uint2*>(&h_hi[0][idx]) = make_uint2(hp0, hp1);
                *reinterpret_cast<uint2*>(&h_lo[0][idx]) = make_uint2(lp0, lp1);
            }
        }
        __syncthreads();                       // h0_new visible

        // ===== layer 1: tanh(b1 + Wih1 @ h0_new + Whh1 @ h1_old) =====
#pragma unroll
        for (int r = 0; r < 16; ++r) { a0[r] = 0.0f; a1[r] = 0.0f; }
        mat_pass32(a0, a1, wih1h, wih1l, h_hi[0], h_lo[0], lane);
        mat_pass32(a0, a1, whh1h, whh1l, h_hi[1], h_lo[1], lane);
        __syncthreads();                       // h1_old reads done
#pragma unroll
        for (int mt = 0; mt < 2; ++mt) {
            const int m = mt * 32 + m31;
            const f32x16& A = mt ? a1 : a0;
#pragma unroll
            for (int rg = 0; rg < 4; ++rg) {
                const int nb4 = n0 + rg * 8 + hb * 4;
                f32x4 b = *reinterpret_cast<const f32x4*>(&cst[2][nb4]);
                float t[4];
#pragma unroll
                for (int r = 0; r < 4; ++r)
                    t[r] = fast_tanh(A[rg * 4 + r] + b[r]);
                unsigned int hp0 = cvt_pk(t[0], t[1]), hp1 = cvt_pk(t[2], t[3]);
                unsigned int lp0 = cvt_pk(t[0] - ubf(hp0 << 16), t[1] - ubf(hp0 & 0xffff0000u));
                unsigned int lp1 = cvt_pk(t[2] - ubf(hp1 << 16), t[3] - ubf(hp1 & 0xffff0000u));
                const int idx = m * HID + (nb4 ^ sx);
                *reinterpret_cast<uint2*>(&h_hi[1][idx]) = make_uint2(hp0, hp1);
                *reinterpret_cast<uint2*>(&h_lo[1][idx]) = make_uint2(lp0, lp1);
            }
        }
        __syncthreads();

        // ===== layer 2: tanh(b2 + Wih2 @ h1_new + Whh2 @ h2_old) + fc partials =====
#pragma unroll
        for (int r = 0; r < 16; ++r) { a0[r] = 0.0f; a1[r] = 0.0f; }
        mat_pass32(a0, a1, wih2h, wih2l, h_hi[1], h_lo[1], lane);
        mat_pass32(a0, a1, whh2h, whh2l, h_hi[2], h_lo[2], lane);
        __syncthreads();                       // h2_old reads done
#pragma unroll
        for (int mt = 0; mt < 2; ++mt) {
            const int m = mt * 32 + m31;
            const f32x16& A = mt ? a1 : a0;
            float o0 = 0.0f, o1 = 0.0f;
#pragma unroll
            for (int rg = 0; rg < 4; ++rg) {
                const int nb4 = n0 + rg * 8 + hb * 4;
                f32x4 b  = *reinterpret_cast<const f32x4*>(&cst[3][nb4]);
                f32x4 f0 = *reinterpret_cast<const f32x4*>(&cst[4][nb4]);
                f32x4 f1 = *reinterpret_cast<const f32x4*>(&cst[5][nb4]);
                float t[4];
#pragma unroll
                for (int r = 0; r < 4; ++r) {
                    t[r] = fast_tanh(A[rg * 4 + r] + b[r]);
                    o0 = fmaf(t[r], f0[r], o0);
                    o1 = fmaf(t[r], f1[r], o1);
                }
                unsigned int hp0 = cvt_pk(t[0], t[1]), hp1 = cvt_pk(t[2], t[3]);
                unsigned int lp0 = cvt_pk(t[0] - ubf(hp0 << 16), t[1] - ubf(hp0 & 0xffff0000u));
                unsigned int lp1 = cvt_pk(t[2] - ubf(hp1 << 16), t[3] - ubf(hp1 & 0xffff0000u));
                const int idx = m * HID + (nb4 ^ sx);
                *reinterpret_cast<uint2*>(&h_hi[2][idx]) = make_uint2(hp0, hp1);
                *reinterpret_cast<uint2*>(&h_lo[2][idx]) = make_uint2(lp0, lp1);
            }
            // combine the two 16-n halves (hb=0/1) of this wave's n-slice
            o0 += __shfl_xor(o0, 32);
            o1 += __shfl_xor(o1, 32);
            if (hb == 0) pfc[wid][m] = make_float2(o0, o1);
        }
        __syncthreads();                       // pfc ready, h2_new visible

        // ===== fc reduce + pos feedback (wave 0) =====
        if (wid == 0) {
            const int m = lane;
            float2 q0 = pfc[0][m], q1 = pfc[1][m], q2 = pfc[2][m], q3 = pfc[3][m];
            float oo0 = fcb0 + q0.x + q1.x + q2.x + q3.x;
            float oo1 = fcb1 + q0.y + q1.y + q2.y + q3.y;
            pbuf[m] = make_float2(oo0, oo1);
            *reinterpret_cast<float2*>(&out[((size_t)s * BATCH + row0 + m) * 2]) =
                make_float2(oo0, oo1);
        }
        __syncthreads();                       // pbuf visible for next step
    }
}

extern "C" void kernel_launch(void* const* d_in, const int* in_sizes, int n_in,
                              void* d_out, int out_size, void* d_ws, size_t ws_size,
                              hipStream_t stream)
{
    const float* raw_ctx  = (const float*)d_in[0];
    const float* obs_traj = (const float*)d_in[1];
    const float* Wih0 = (const float*)d_in[2];
    const float* Whh0 = (const float*)d_in[3];
    const float* bih0 = (const float*)d_in[4];
    const float* bhh0 = (const float*)d_in[5];
    const float* Wih1 = (const float*)d_in[6];
    const float* Whh1 = (const float*)d_in[7];
    const float* bih1 = (const float*)d_in[8];
    const float* bhh1 = (const float*)d_in[9];
    const float* Wih2 = (const float*)d_in[10];
    const float* Whh2 = (const float*)d_in[11];
    const float* bih2 = (const float*)d_in[12];
    const float* bhh2 = (const float*)d_in[13];
    const float* fcW  = (const float*)d_in[14];
    const float* fcb  = (const float*)d_in[15];
    float* out = (float*)d_out;

    dim3 grid(BATCH / BM);   // 1024 blocks
    dim3 block(NTHREADS);    // 256 threads = 4 waves
    rnn_head_kernel<<<grid, block, 0, stream>>>(
        raw_ctx, obs_traj,
        Wih0, Whh0, bih0, bhh0,
        Wih1, Whh1, bih1, bhh1,
        Wih2, Whh2, bih2, bhh2,
        fcW, fcb, out);
}

// Round 6
// 659.014 us; speedup vs baseline: 1.1622x; 1.1622x over previous
//
#include <hip/hip_runtime.h>
#include <cstdint>
#include <cstddef>

// PaperRNNHead on MI355X — R6: r4 frame (8 waves, n16, BM=64, persistent
// split-bf16 weights) with a restructured step schedule to fix phase
// serialization (r4/r5 lesson: latency-bound, not LDS-throughput-bound):
//  - 4 barriers/step (was 8)
//  - region A: TWO independent mat_passes (Whh0@h0_old + Whh1@h1_old)
//  - region C: Wih1@h0_new + Whh2@h2_old (h2_old stable until D writes it)
//  - tanh/pack VALU before each barrier (overlaps other waves' LDS reads)
//  - fc: in-register partials + shfl_xor(16/32) + pfc LDS exchange; pos
//    feedback distributed by __shfl — no h2 re-read, no 2-wave-only phase.

#define BATCH    65536
#define CTXF     512
#define INF      514
#define HID      128
#define PREDL    12
#define OBSL     8
#define BM       64
#define NTHREADS 512

typedef __attribute__((ext_vector_type(8))) short s16x8;
typedef __attribute__((ext_vector_type(4))) float f32x4;

#define MFMA16(a, b, c) __builtin_amdgcn_mfma_f32_16x16x32_bf16((a), (b), (c), 0, 0, 0)

__device__ __forceinline__ unsigned int cvt_pk(float a, float b) {
    unsigned int r;
    asm("v_cvt_pk_bf16_f32 %0, %1, %2" : "=v"(r) : "v"(a), "v"(b));
    return r;  // [15:0] = bf16(a), [31:16] = bf16(b)
}
__device__ __forceinline__ float ubf(unsigned int bits) { return __uint_as_float(bits); }

union Frag { unsigned int u[4]; s16x8 v; };

__device__ __forceinline__ void split8(const float* x, s16x8& hi, s16x8& lo) {
    Frag H, L;
#pragma unroll
    for (int i = 0; i < 4; ++i) {
        unsigned int hp = cvt_pk(x[2 * i], x[2 * i + 1]);
        float r0 = x[2 * i]     - ubf(hp << 16);
        float r1 = x[2 * i + 1] - ubf(hp & 0xffff0000u);
        H.u[i] = hp;
        L.u[i] = cvt_pk(r0, r1);
    }
    hi = H.v; lo = L.v;
}

__device__ __forceinline__ float fast_tanh(float x) {
    float e = __expf(x + x);
    float r = __builtin_amdgcn_rcpf(e + 1.0f);
    return fmaf(-2.0f, r, 1.0f);
}

__device__ __forceinline__ void load_w(const float* __restrict__ W, int ldw,
                                       int n0, int lane, s16x8* hi, s16x8* lo) {
    const float* base = W + (size_t)(n0 + (lane & 15)) * ldw + ((lane >> 4) * 8);
#pragma unroll
    for (int kt = 0; kt < 4; ++kt) {
        float x[8];
        *(float4*)(x)     = *(const float4*)(base + kt * 32);
        *(float4*)(x + 4) = *(const float4*)(base + kt * 32 + 4);
        split8(x, hi[kt], lo[kt]);
    }
}

// acc[g] += W (wave's 16 n-rows, reg frags) x h (B from swizzled LDS planes)
__device__ __forceinline__ void mat_pass(f32x4* acc,
                                         const s16x8* whi, const s16x8* wlo,
                                         const unsigned short* __restrict__ phi,
                                         const unsigned short* __restrict__ plo,
                                         int lane) {
    const int i15 = lane & 15;
    const int sx  = (i15 & 7) << 3;
    const int kb0 = (lane >> 4) * 8;
#pragma unroll
    for (int kt = 0; kt < 4; ++kt) {
        const int kbs = (kt * 32 + kb0) ^ sx;
#pragma unroll
        for (int g = 0; g < 4; ++g) {
            const int idx = (g * 16 + i15) * HID + kbs;
            s16x8 bh = *reinterpret_cast<const s16x8*>(&phi[idx]);
            s16x8 bl = *reinterpret_cast<const s16x8*>(&plo[idx]);
            acc[g] = MFMA16(whi[kt], bh, acc[g]);
            acc[g] = MFMA16(whi[kt], bl, acc[g]);
            acc[g] = MFMA16(wlo[kt], bh, acc[g]);
        }
    }
}

// cst rows: 0=b1, 1=b2, 2=fcw0, 3=fcw1
__global__ void __launch_bounds__(NTHREADS, 2)
rnn_head_kernel(const float* __restrict__ raw_ctx,
                const float* __restrict__ obs_traj,
                const float* __restrict__ Wih0, const float* __restrict__ Whh0,
                const float* __restrict__ bih0, const float* __restrict__ bhh0,
                const float* __restrict__ Wih1, const float* __restrict__ Whh1,
                const float* __restrict__ bih1, const float* __restrict__ bhh1,
                const float* __restrict__ Wih2, const float* __restrict__ Whh2,
                const float* __restrict__ bih2, const float* __restrict__ bhh2,
                const float* __restrict__ fcW,  const float* __restrict__ fcb,
                float* __restrict__ out)
{
    __shared__ __align__(16) unsigned short h_hi[3][BM * HID];   // 48 KB
    __shared__ __align__(16) unsigned short h_lo[3][BM * HID];   // 48 KB
    __shared__ __align__(16) float ctx_s[BM][132];               // 33.8 KB
    __shared__ __align__(16) float cst[4][HID];                  // 2 KB
    __shared__ float2 pfc[8][BM];                                // 4 KB

    const int tid  = threadIdx.x;
    const int lane = tid & 63;
    const int wid  = __builtin_amdgcn_readfirstlane(tid >> 6);
    const int n0   = wid * 16;
    const int row0 = blockIdx.x * BM;
    const int i15  = lane & 15;
    const int h4   = lane >> 4;
    const int nb   = n0 + h4 * 4;
    const int sx   = (i15 & 7) << 3;
    const int nbs  = nb ^ sx;

    // ---------- per-lane fp32 constants (kept in regs: used with shfl'd pos) ----------
    f32x4 b0, wp0, wp1;
#pragma unroll
    for (int r = 0; r < 4; ++r) {
        b0[r]  = bih0[nb + r] + bhh0[nb + r];
        wp0[r] = Wih0[(size_t)(nb + r) * INF + 512];
        wp1[r] = Wih0[(size_t)(nb + r) * INF + 513];
    }
    const float fcb0 = fcb[0], fcb1 = fcb[1];

    // ---------- init LDS ----------
    if (tid < HID) {
        cst[0][tid] = bih1[tid] + bhh1[tid];
        cst[1][tid] = bih2[tid] + bhh2[tid];
        cst[2][tid] = fcW[tid];
        cst[3][tid] = fcW[HID + tid];
    }
    for (int i = tid; i < 3 * BM * HID / 2; i += NTHREADS) {
        ((unsigned int*)h_hi)[i] = 0u;
        ((unsigned int*)h_lo)[i] = 0u;
    }
    // pos feedback registers (every lane: its m = lane)
    float2 pv = *reinterpret_cast<const float2*>(
        &obs_traj[((size_t)(OBSL - 1) * BATCH + row0 + lane) * 2]);
    float o0 = pv.x, o1 = pv.y;

    // ---------- ctx projection: ctxc = b0 + raw_ctx @ Wih0[:, :512].T ----------
    f32x4 ctxc[4];
#pragma unroll
    for (int g = 0; g < 4; ++g) ctxc[g] = b0;

#pragma unroll 1
    for (int kc = 0; kc < CTXF; kc += 128) {
        s16x8 cah[4], cal[4];
        {
            const float* base = Wih0 + (size_t)(n0 + i15) * INF + kc + h4 * 8;
#pragma unroll
            for (int kt = 0; kt < 4; ++kt) {
                float x[8];
                *(float4*)(x)     = *(const float4*)(base + kt * 32);
                *(float4*)(x + 4) = *(const float4*)(base + kt * 32 + 4);
                split8(x, cah[kt], cal[kt]);
            }
        }
        __syncthreads();
        {
            const int rr = tid >> 3, seg = (tid & 7) * 16;
            const float* src = raw_ctx + (size_t)(row0 + rr) * CTXF + kc + seg;
            float4 v0 = ((const float4*)src)[0], v1 = ((const float4*)src)[1];
            float4 v2 = ((const float4*)src)[2], v3 = ((const float4*)src)[3];
            float* dst = &ctx_s[rr][seg];
            ((float4*)dst)[0] = v0; ((float4*)dst)[1] = v1;
            ((float4*)dst)[2] = v2; ((float4*)dst)[3] = v3;
        }
        __syncthreads();
#pragma unroll
        for (int kt = 0; kt < 4; ++kt) {
#pragma unroll
            for (int g = 0; g < 4; ++g) {
                const int m = g * 16 + i15;
                const float* xp = &ctx_s[m][kt * 32 + h4 * 8];
                float x[8];
                *(float4*)(x)     = *(const float4*)(xp);
                *(float4*)(x + 4) = *(const float4*)(xp + 4);
                s16x8 bh, bl;
                split8(x, bh, bl);
                ctxc[g] = MFMA16(cah[kt], bh, ctxc[g]);
                ctxc[g] = MFMA16(cah[kt], bl, ctxc[g]);
                ctxc[g] = MFMA16(cal[kt], bh, ctxc[g]);
            }
        }
    }

    // ---------- persistent weight fragments ----------
    s16x8 whh0h[4], whh0l[4], wih1h[4], wih1l[4], whh1h[4], whh1l[4];
    s16x8 wih2h[4], wih2l[4], whh2h[4], whh2l[4];
    load_w(Whh0, HID, n0, lane, whh0h, whh0l);
    load_w(Wih1, HID, n0, lane, wih1h, wih1l);
    load_w(Whh1, HID, n0, lane, whh1h, whh1l);
    load_w(Wih2, HID, n0, lane, wih2h, wih2l);
    load_w(Whh2, HID, n0, lane, whh2h, whh2l);

    __syncthreads();   // h zeroed, cst visible

    // ---------- 12 recurrent steps, 4 barriers each ----------
#pragma unroll 1
    for (int s = 0; s < PREDL; ++s) {
        f32x4 acc0[4], acc1[4], acc2[4];

        // ===== region A: Whh0@h0_old + Whh1@h1_old; tanh0 =====
#pragma unroll
        for (int g = 0; g < 4; ++g) {
            const float pxg = __shfl(o0, g * 16 + i15);
            const float pyg = __shfl(o1, g * 16 + i15);
            f32x4 a = ctxc[g];
#pragma unroll
            for (int r = 0; r < 4; ++r) {
                a[r] = fmaf(pxg, wp0[r], a[r]);
                a[r] = fmaf(pyg, wp1[r], a[r]);
            }
            acc0[g] = a;
            f32x4 z; z[0] = 0.f; z[1] = 0.f; z[2] = 0.f; z[3] = 0.f;
            acc1[g] = z;
        }
        mat_pass(acc0, whh0h, whh0l, h_hi[0], h_lo[0], lane);
        mat_pass(acc1, whh1h, whh1l, h_hi[1], h_lo[1], lane);
        unsigned int pk0[4][4];           // packed h0_new (hi0,hi1,lo0,lo1 per g)
#pragma unroll
        for (int g = 0; g < 4; ++g) {
            float t0 = fast_tanh(acc0[g][0]), t1 = fast_tanh(acc0[g][1]);
            float t2 = fast_tanh(acc0[g][2]), t3 = fast_tanh(acc0[g][3]);
            unsigned int hp0 = cvt_pk(t0, t1), hp1 = cvt_pk(t2, t3);
            pk0[g][0] = hp0; pk0[g][1] = hp1;
            pk0[g][2] = cvt_pk(t0 - ubf(hp0 << 16), t1 - ubf(hp0 & 0xffff0000u));
            pk0[g][3] = cvt_pk(t2 - ubf(hp1 << 16), t3 - ubf(hp1 & 0xffff0000u));
        }
        __syncthreads();                   // all reads of h0/h1_old done

        // ===== region B: publish h0_new =====
#pragma unroll
        for (int g = 0; g < 4; ++g) {
            const int mi = (g * 16 + i15) * HID + nbs;
            *reinterpret_cast<uint2*>(&h_hi[0][mi]) = make_uint2(pk0[g][0], pk0[g][1]);
            *reinterpret_cast<uint2*>(&h_lo[0][mi]) = make_uint2(pk0[g][2], pk0[g][3]);
        }
        __syncthreads();                   // h0_new visible

        // ===== region C: Wih1@h0_new + Whh2@h2_old; tanh1; publish h1_new =====
#pragma unroll
        for (int g = 0; g < 4; ++g) {
            f32x4 z; z[0] = 0.f; z[1] = 0.f; z[2] = 0.f; z[3] = 0.f;
            acc2[g] = z;
        }
        mat_pass(acc1, wih1h, wih1l, h_hi[0], h_lo[0], lane);
        mat_pass(acc2, whh2h, whh2l, h_hi[2], h_lo[2], lane);
#pragma unroll
        for (int g = 0; g < 4; ++g) {
            f32x4 b = *reinterpret_cast<const f32x4*>(&cst[0][nb]);
            float t0 = fast_tanh(acc1[g][0] + b[0]), t1 = fast_tanh(acc1[g][1] + b[1]);
            float t2 = fast_tanh(acc1[g][2] + b[2]), t3 = fast_tanh(acc1[g][3] + b[3]);
            unsigned int hp0 = cvt_pk(t0, t1), hp1 = cvt_pk(t2, t3);
            unsigned int lp0 = cvt_pk(t0 - ubf(hp0 << 16), t1 - ubf(hp0 & 0xffff0000u));
            unsigned int lp1 = cvt_pk(t2 - ubf(hp1 << 16), t3 - ubf(hp1 & 0xffff0000u));
            const int mi = (g * 16 + i15) * HID + nbs;
            *reinterpret_cast<uint2*>(&h_hi[1][mi]) = make_uint2(hp0, hp1);
            *reinterpret_cast<uint2*>(&h_lo[1][mi]) = make_uint2(lp0, lp1);
        }
        __syncthreads();                   // h1_new visible (h2_old reads done)

        // ===== region D: Wih2@h1_new; tanh2; publish h2_new; fc partials =====
        mat_pass(acc2, wih2h, wih2l, h_hi[1], h_lo[1], lane);
#pragma unroll
        for (int g = 0; g < 4; ++g) {
            f32x4 b  = *reinterpret_cast<const f32x4*>(&cst[1][nb]);
            f32x4 f0 = *reinterpret_cast<const f32x4*>(&cst[2][nb]);
            f32x4 f1 = *reinterpret_cast<const f32x4*>(&cst[3][nb]);
            float t[4];
            float p0 = 0.f, p1 = 0.f;
#pragma unroll
            for (int r = 0; r < 4; ++r) {
                t[r] = fast_tanh(acc2[g][r] + b[r]);
                p0 = fmaf(t[r], f0[r], p0);
                p1 = fmaf(t[r], f1[r], p1);
            }
            unsigned int hp0 = cvt_pk(t[0], t[1]), hp1 = cvt_pk(t[2], t[3]);
            unsigned int lp0 = cvt_pk(t[0] - ubf(hp0 << 16), t[1] - ubf(hp0 & 0xffff0000u));
            unsigned int lp1 = cvt_pk(t[2] - ubf(hp1 << 16), t[3] - ubf(hp1 & 0xffff0000u));
            const int mi = (g * 16 + i15) * HID + nbs;
            *reinterpret_cast<uint2*>(&h_hi[2][mi]) = make_uint2(hp0, hp1);
            *reinterpret_cast<uint2*>(&h_lo[2][mi]) = make_uint2(lp0, lp1);
            // reduce fc partial over the 4 k-chunk lanes (h4) of this m-column
            p0 += __shfl_xor(p0, 16); p0 += __shfl_xor(p0, 32);
            p1 += __shfl_xor(p1, 16); p1 += __shfl_xor(p1, 32);
            if (h4 == 0) pfc[wid][g * 16 + i15] = make_float2(p0, p1);
        }
        __syncthreads();                   // pfc + h2_new visible

        // ===== step tail: fc reduce, out store, pos feedback =====
        {
            float s0 = fcb0, s1 = fcb1;
#pragma unroll
            for (int w = 0; w < 8; ++w) {
                float2 q = pfc[w][lane];
                s0 += q.x; s1 += q.y;
            }
            o0 = s0; o1 = s1;
            if (wid == 0) {
                *reinterpret_cast<float2*>(&out[((size_t)s * BATCH + row0 + lane) * 2]) =
                    make_float2(s0, s1);
            }
        }
        // no barrier needed: pfc next written in region D, 3 barriers away
    }
}

extern "C" void kernel_launch(void* const* d_in, const int* in_sizes, int n_in,
                              void* d_out, int out_size, void* d_ws, size_t ws_size,
                              hipStream_t stream)
{
    const float* raw_ctx  = (const float*)d_in[0];
    const float* obs_traj = (const float*)d_in[1];
    const float* Wih0 = (const float*)d_in[2];
    const float* Whh0 = (const float*)d_in[3];
    const float* bih0 = (const float*)d_in[4];
    const float* bhh0 = (const float*)d_in[5];
    const float* Wih1 = (const float*)d_in[6];
    const float* Whh1 = (const float*)d_in[7];
    const float* bih1 = (const float*)d_in[8];
    const float* bhh1 = (const float*)d_in[9];
    const float* Wih2 = (const float*)d_in[10];
    const float* Whh2 = (const float*)d_in[11];
    const float* bih2 = (const float*)d_in[12];
    const float* bhh2 = (const float*)d_in[13];
    const float* fcW  = (const float*)d_in[14];
    const float* fcb  = (const float*)d_in[15];
    float* out = (float*)d_out;

    dim3 grid(BATCH / BM);   // 1024 blocks
    dim3 block(NTHREADS);    // 512 threads = 8 waves
    rnn_head_kernel<<<grid, block, 0, stream>>>(
        raw_ctx, obs_traj,
        Wih0, Whh0, bih0, bhh0,
        Wih1, Whh1, bih1, bhh1,
        Wih2, Whh2, bih2, bhh2,
        fcW, fcb, out);
}